// Round 10
// baseline (86.964 us; speedup 1.0000x reference)
//
#include <hip/hip_runtime.h>
#include <cstddef>

// Shapes: B=4, H=W=D=16, C=32, N=4096, Dout=13; out (4,16,16,13,32) f32.

typedef float f32x4 __attribute__((ext_vector_type(4)));
typedef short s16x8 __attribute__((ext_vector_type(8)));

#define SQRT_LOG2E 1.2011224087864498f   // xb scaled so QK^T lands in exp2 domain
#define C2SHIFT    57.70780163555854f    // 40*log2(e)

// RNE f32->bf16 pack of two floats into one u32 (low = first arg). Proven R1-R9.
__device__ inline unsigned pk2(float a, float b) {
  union { float f; unsigned u; } ca, cb;
  ca.f = a; cb.f = b;
  unsigned ra = (ca.u + 0x7fffu + ((ca.u >> 16) & 1u)) >> 16;
  unsigned rb = (cb.u + 0x7fffu + ((cb.u >> 16) & 1u)) >> 16;
  return ra | (rb << 16);
}

// ---------------------------------------------------------------------------
// Kernel A: blocks 0..255 = prep (xb scaled bf16, xtf X^T A-frag tiles);
// blocks 256..259 = per-batch Gram (raw x) + algebra with ALL weights staged
// in LDS (fix for the 51us global-scalar-latency tail seen in R9 profile).
// ---------------------------------------------------------------------------
__global__ __launch_bounds__(256) void k_prepalg(
    const float* __restrict__ x,
    const float* __restrict__ wq, const float* __restrict__ bq,
    const float* __restrict__ wk, const float* __restrict__ bk,
    const float* __restrict__ wv, const float* __restrict__ bv,
    const float* __restrict__ gamma,
    const float* __restrict__ wpos, const float* __restrict__ bpos,
    ushort* __restrict__ xb, ushort* __restrict__ xtf,
    float* __restrict__ w2, float* __restrict__ b2)
{
  __shared__ float G[1024], s[32], t1[1024], att[1024], M[1024], mvec[32];
  __shared__ float wqS[1024], wkS[1024], wvS[1024], wpoS[4096];
  int bx = blockIdx.x;
  int tid = threadIdx.x;
  if (bx < 256) {
    // ---- prep (proven body) ----
    int t = bx * 256 + tid;                        // 0..65535
    const float4* xs = (const float4*)x;
    float4 v0 = xs[2 * t], v1 = xs[2 * t + 1];
    uint4 o;
    o.x = pk2(v0.x * SQRT_LOG2E, v0.y * SQRT_LOG2E);
    o.y = pk2(v0.z * SQRT_LOG2E, v0.w * SQRT_LOG2E);
    o.z = pk2(v1.x * SQRT_LOG2E, v1.y * SQRT_LOG2E);
    o.w = pk2(v1.z * SQRT_LOG2E, v1.w * SQRT_LOG2E);
    ((uint4*)xb)[t] = o;

    int b = t >> 14, r2 = t & 16383;
    int ktile = r2 >> 7, r3 = r2 & 127;
    int h = r3 >> 6, lane = r3 & 63;
    int g = lane >> 4, c = h * 16 + (lane & 15);
    const float* src = x + (((size_t)b * 4096 + ktile * 32 + 8 * g) * 32 + c);
    float w[8];
#pragma unroll
    for (int j = 0; j < 8; ++j) w[j] = src[(size_t)j * 32];
    uint4 u;
    u.x = pk2(w[0], w[1]); u.y = pk2(w[2], w[3]);
    u.z = pk2(w[4], w[5]); u.w = pk2(w[6], w[7]);
    ((uint4*)xtf)[(size_t)((b * 128 + ktile) * 2 + h) * 64 + lane] = u;
    return;
  }

  // ---- Gram + algebra for b = bx-256 ----
  int b = bx - 256;
  int wid = tid >> 6, lane = tid & 63, g = lane >> 4, c16 = lane & 15;
  // stage weights -> LDS (coalesced, once)
  ((float4*)wqS)[tid] = ((const float4*)wq)[tid];
  ((float4*)wkS)[tid] = ((const float4*)wk)[tid];
  ((float4*)wvS)[tid] = ((const float4*)wv)[tid];
#pragma unroll
  for (int i = 0; i < 4; ++i)
    ((float4*)wpoS)[tid + 256 * i] = ((const float4*)wpos)[tid + 256 * i];
  for (int i = tid; i < 1024; i += 256) G[i] = 0.f;
  if (tid < 32) s[tid] = 0.f;
  __syncthreads();

  f32x4 z = {0.f, 0.f, 0.f, 0.f};
  f32x4 G00 = z, G01 = z, G10 = z, G11 = z, s0 = z, s1 = z;
  s16x8 ones;
#pragma unroll
  for (int j = 0; j < 8; ++j) ones[j] = (short)0x3F80;
  for (int t = wid * 32; t < wid * 32 + 32; ++t) {
    s16x8 fr[2];
#pragma unroll
    for (int h = 0; h < 2; ++h) {
      const float* src = x + (((size_t)b * 4096 + t * 32 + 8 * g) * 32 + h * 16 + c16);
      float w[8];
#pragma unroll
      for (int j = 0; j < 8; ++j) w[j] = src[(size_t)j * 32];
      uint4 u = make_uint4(pk2(w[0], w[1]), pk2(w[2], w[3]),
                           pk2(w[4], w[5]), pk2(w[6], w[7]));
      fr[h] = __builtin_bit_cast(s16x8, u);
    }
    G00 = __builtin_amdgcn_mfma_f32_16x16x32_bf16(fr[0], fr[0], G00, 0, 0, 0);
    G01 = __builtin_amdgcn_mfma_f32_16x16x32_bf16(fr[0], fr[1], G01, 0, 0, 0);
    G10 = __builtin_amdgcn_mfma_f32_16x16x32_bf16(fr[1], fr[0], G10, 0, 0, 0);
    G11 = __builtin_amdgcn_mfma_f32_16x16x32_bf16(fr[1], fr[1], G11, 0, 0, 0);
    s0  = __builtin_amdgcn_mfma_f32_16x16x32_bf16(fr[0], ones, s0, 0, 0, 0);
    s1  = __builtin_amdgcn_mfma_f32_16x16x32_bf16(fr[1], ones, s1, 0, 0, 0);
  }
#pragma unroll
  for (int hr = 0; hr < 2; ++hr)
#pragma unroll
    for (int hc = 0; hc < 2; ++hc) {
      f32x4 v = hr ? (hc ? G11 : G10) : (hc ? G01 : G00);
#pragma unroll
      for (int r = 0; r < 4; ++r)
        atomicAdd(&G[(16 * hr + 4 * g + r) * 32 + 16 * hc + c16], v[r]);
    }
  if (c16 == 0) {
#pragma unroll
    for (int hr = 0; hr < 2; ++hr) {
      f32x4 v = hr ? s1 : s0;
#pragma unroll
      for (int r = 0; r < 4; ++r) atomicAdd(&s[16 * hr + 4 * g + r], v[r]);
    }
  }
  __syncthreads();

  // stage B (all-LDS operands): f = tid&31, c = (tid>>5) + 8*pass
  int f = tid & 31, cq = tid >> 5;
#pragma unroll
  for (int p = 0; p < 4; ++p) {
    int c = cq + 8 * p;
    float t = 0.f;
#pragma unroll
    for (int j = 0; j < 32; ++j) t = fmaf(G[c * 32 + j], wkS[j * 32 + f], t);
    t1[c * 32 + f] = t;
  }
  __syncthreads();
  float swk = 0.f;
#pragma unroll
  for (int j = 0; j < 32; ++j) swk = fmaf(s[j], wkS[j * 32 + f], swk);
  float bkf = bk[f];
#pragma unroll
  for (int p = 0; p < 4; ++p) {
    int c = cq + 8 * p;
    float swq = 0.f;
#pragma unroll
    for (int j = 0; j < 32; ++j) swq = fmaf(s[j], wqS[j * 32 + c], swq);
    float e = 0.f;
#pragma unroll
    for (int i = 0; i < 32; ++i) e = fmaf(wqS[i * 32 + c], t1[i * 32 + f], e);
    e += bq[c] * (swk + 4096.f * bkf) + swq * bkf;
    float m_ = e;
    for (int off = 16; off; off >>= 1) m_ = fmaxf(m_, __shfl_xor(m_, off, 32));
    float pr = __expf(e - m_);
    float sum = pr;
    for (int off = 16; off; off >>= 1) sum += __shfl_xor(sum, off, 32);
    att[c * 32 + f] = pr / sum;
  }
  __syncthreads();
#pragma unroll
  for (int p = 0; p < 4; ++p) {
    int c = cq + 8 * p;
    float mm = 0.f;
#pragma unroll
    for (int j = 0; j < 32; ++j) mm = fmaf(wvS[c * 32 + j], att[f * 32 + j], mm);
    M[c * 32 + f] = mm;
  }
  if (tid < 32) {
    float mv = 0.f;
#pragma unroll
    for (int j = 0; j < 32; ++j) mv = fmaf(bv[j], att[tid * 32 + j], mv);
    mvec[tid] = mv;
  }
  __syncthreads();
  float gam = gamma[0];
#pragma unroll
  for (int p = 0; p < 4; ++p) {
    int c = cq + 8 * p;
    for (int kd = 0; kd < 4; ++kd) {
      float acc = 0.f;
#pragma unroll
      for (int j = 0; j < 32; ++j)
        acc = fmaf(M[c * 32 + j], wpoS[(kd * 32 + j) * 32 + f], acc);
      w2[((b * 4 + kd) * 32 + c) * 32 + f] = gam * acc + wpoS[(kd * 32 + c) * 32 + f];
    }
  }
  if (tid < 32) {
    float acc = 0.f;
#pragma unroll
    for (int kd = 0; kd < 4; ++kd)
#pragma unroll
      for (int j = 0; j < 32; ++j)
        acc = fmaf(mvec[j], wpoS[(kd * 32 + j) * 32 + tid], acc);
    b2[b * 32 + tid] = gam * acc + bpos[tid];
  }
}

// ---------------------------------------------------------------------------
// Kernel B: fused flash + conv. 512 thr (8 waves, 2/SIMD): wave-group kh owns
// half the keys (fixed-shift softmax => partials are ADDITIVE), LDS combine.
// k-loop unrolled x2 (8 b128 loads in flight). grid (64 rowgroups, 4 b).
// ---------------------------------------------------------------------------
__global__ __launch_bounds__(512) void k_fused(
    const ushort* __restrict__ xb, const ushort* __restrict__ xtf,
    const float* __restrict__ x, const float* __restrict__ beta,
    const float* __restrict__ wch, const float* __restrict__ bch,
    const float* __restrict__ w2, const float* __restrict__ b2,
    float* __restrict__ out)
{
  __shared__ float sS[64][32];                     // beta * attnout / L
  __shared__ f32x4 pO0[4][64], pO1[4][64];
  __shared__ float pL[4][64];
  __shared__ float4 wcS[1024], wpS[1024];
  __shared__ float bcS[32], bpS[32];
  int rg = blockIdx.x, b = blockIdx.y, tid = threadIdx.x;
  for (int i = tid; i < 1024; i += 512) {
    wcS[i] = ((const float4*)wch)[i];
    wpS[i] = ((const float4*)(w2 + (size_t)b * 4096))[i];
  }
  if (tid < 32) { bcS[tid] = bch[tid]; bpS[tid] = b2[b * 32 + tid]; }

  int wid = tid >> 6, lane = tid & 63, g = lane >> 4, c16 = lane & 15;
  int wid2 = wid & 3, kh = wid >> 2;               // row-group, key-half
  int qw = rg * 64 + wid2 * 16;
  const ushort* xbb = xb + ((size_t)b << 17);
  const ushort* xtb = xtf + (size_t)b * 131072;

  s16x8 qA = *(const s16x8*)(xbb + (qw + c16) * 32 + 8 * g);
  f32x4 z = {0.f, 0.f, 0.f, 0.f};
  f32x4 minit = {-C2SHIFT, -C2SHIFT, -C2SHIFT, -C2SHIFT};
  f32x4 oA0 = z, oA1 = z, lac = z;
  s16x8 ones;
#pragma unroll
  for (int j = 0; j < 8; ++j) ones[j] = (short)0x3F80;
  int kap = ((c16 >> 2) << 3) + (c16 & 3);         // kappa(c16)
  int k0 = kh * 2048;

  for (int kt = k0; kt < k0 + 2048; kt += 64) {
    // issue all 8 b128 loads for both 32-key subtiles up front
    const ushort* kra = xbb + (size_t)kt * 32;
    const ushort* krb = xbb + (size_t)(kt + 32) * 32;
    s16x8 kf0a = *(const s16x8*)(kra + (size_t)kap * 32 + 8 * g);
    s16x8 kf1a = *(const s16x8*)(kra + (size_t)(kap + 4) * 32 + 8 * g);
    s16x8 kf0b = *(const s16x8*)(krb + (size_t)kap * 32 + 8 * g);
    s16x8 kf1b = *(const s16x8*)(krb + (size_t)(kap + 4) * 32 + 8 * g);
    const ushort* xt = xtb + (size_t)(kt >> 5) * 1024 + lane * 8;
    s16x8 a0a = *(const s16x8*)(xt);
    s16x8 a1a = *(const s16x8*)(xt + 512);
    s16x8 a0b = *(const s16x8*)(xt + 1024);
    s16x8 a1b = *(const s16x8*)(xt + 1536);

    f32x4 e0 = __builtin_amdgcn_mfma_f32_16x16x32_bf16(kf0a, qA, minit, 0, 0, 0);
    f32x4 e1 = __builtin_amdgcn_mfma_f32_16x16x32_bf16(kf1a, qA, minit, 0, 0, 0);
    f32x4 e2 = __builtin_amdgcn_mfma_f32_16x16x32_bf16(kf0b, qA, minit, 0, 0, 0);
    f32x4 e3 = __builtin_amdgcn_mfma_f32_16x16x32_bf16(kf1b, qA, minit, 0, 0, 0);
    f32x4 p0, p1, p2, p3;
#pragma unroll
    for (int r = 0; r < 4; ++r) {
      p0[r] = __builtin_amdgcn_exp2f(e0[r]);
      p1[r] = __builtin_amdgcn_exp2f(e1[r]);
      p2[r] = __builtin_amdgcn_exp2f(e2[r]);
      p3[r] = __builtin_amdgcn_exp2f(e3[r]);
    }
    uint4 uA = make_uint4(pk2(p0[0], p0[1]), pk2(p0[2], p0[3]),
                          pk2(p1[0], p1[1]), pk2(p1[2], p1[3]));
    uint4 uB = make_uint4(pk2(p2[0], p2[1]), pk2(p2[2], p2[3]),
                          pk2(p3[0], p3[1]), pk2(p3[2], p3[3]));
    s16x8 fpa = __builtin_bit_cast(s16x8, uA);
    s16x8 fpb = __builtin_bit_cast(s16x8, uB);

    oA0 = __builtin_amdgcn_mfma_f32_16x16x32_bf16(a0a, fpa, oA0, 0, 0, 0);
    oA1 = __builtin_amdgcn_mfma_f32_16x16x32_bf16(a1a, fpa, oA1, 0, 0, 0);
    lac = __builtin_amdgcn_mfma_f32_16x16x32_bf16(ones, fpa, lac, 0, 0, 0);
    oA0 = __builtin_amdgcn_mfma_f32_16x16x32_bf16(a0b, fpb, oA0, 0, 0, 0);
    oA1 = __builtin_amdgcn_mfma_f32_16x16x32_bf16(a1b, fpb, oA1, 0, 0, 0);
    lac = __builtin_amdgcn_mfma_f32_16x16x32_bf16(ones, fpb, lac, 0, 0, 0);
  }

  // combine the two key-halves (additive: fixed softmax shift, no max-rescale)
  if (kh == 1) {
    pO0[wid2][lane] = oA0;
    pO1[wid2][lane] = oA1;
    pL[wid2][lane] = lac[0];
  }
  __syncthreads();
  if (kh == 0) {
    f32x4 q0 = pO0[wid2][lane], q1 = pO1[wid2][lane];
    float L = lac[0] + pL[wid2][lane];
    float sc = beta[0] / L;
    int rloc = wid2 * 16 + c16;
    f32x4 v0, v1;
#pragma unroll
    for (int r = 0; r < 4; ++r) {
      v0[r] = (oA0[r] + q0[r]) * sc;
      v1[r] = (oA1[r] + q1[r]) * sc;
    }
    *(f32x4*)&sS[rloc][4 * g] = v0;
    *(f32x4*)&sS[rloc][16 + 4 * g] = v1;
  }
  __syncthreads();

  // conv3d(1,1,4) + relu both branches; ca = sS + x re-derived on the fly.
  if (tid < 208) {
    int row2 = tid >> 2, fq = tid & 3;             // 52 rows x 4 f-quarters
    int hw_l = row2 / 13, dout = row2 % 13;
    int rbase = hw_l * 16 + dout;
    size_t xrow = ((size_t)b * 4096 + (size_t)(rg * 4 + hw_l) * 16 + dout) * 32;
    float accC[8], accP[8];
#pragma unroll
    for (int j = 0; j < 8; ++j) { accC[j] = bcS[fq * 8 + j]; accP[j] = bpS[fq * 8 + j]; }
    for (int kd = 0; kd < 4; ++kd) {
      const float4* xr4 = (const float4*)(x + xrow + (size_t)kd * 32);
      const float* srow = sS[rbase + kd];
#pragma unroll
      for (int c4 = 0; c4 < 8; ++c4) {
        float4 xv = xr4[c4];
#pragma unroll
        for (int e = 0; e < 4; ++e) {
          float xve = (e == 0 ? xv.x : e == 1 ? xv.y : e == 2 ? xv.z : xv.w);
          float cve = srow[4 * c4 + e] + xve;      // ca = beta*o/L + x
          int wbase = (kd * 32 + 4 * c4 + e) * 8 + fq * 2;
          float4 w1a = wcS[wbase], w1b = wcS[wbase + 1];
          accC[0] = fmaf(cve, w1a.x, accC[0]);
          accC[1] = fmaf(cve, w1a.y, accC[1]);
          accC[2] = fmaf(cve, w1a.z, accC[2]);
          accC[3] = fmaf(cve, w1a.w, accC[3]);
          accC[4] = fmaf(cve, w1b.x, accC[4]);
          accC[5] = fmaf(cve, w1b.y, accC[5]);
          accC[6] = fmaf(cve, w1b.z, accC[6]);
          accC[7] = fmaf(cve, w1b.w, accC[7]);
          float4 w2a = wpS[wbase], w2b = wpS[wbase + 1];
          accP[0] = fmaf(xve, w2a.x, accP[0]);
          accP[1] = fmaf(xve, w2a.y, accP[1]);
          accP[2] = fmaf(xve, w2a.z, accP[2]);
          accP[3] = fmaf(xve, w2a.w, accP[3]);
          accP[4] = fmaf(xve, w2b.x, accP[4]);
          accP[5] = fmaf(xve, w2b.y, accP[5]);
          accP[6] = fmaf(xve, w2b.z, accP[6]);
          accP[7] = fmaf(xve, w2b.w, accP[7]);
        }
      }
    }
    int gid = b * 3328 + (rg * 4 + hw_l) * 13 + dout;
    float* orow = out + (size_t)gid * 32 + fq * 8;
    float4 o0, o1;
    o0.x = fmaxf(accC[0], 0.f) + fmaxf(accP[0], 0.f);
    o0.y = fmaxf(accC[1], 0.f) + fmaxf(accP[1], 0.f);
    o0.z = fmaxf(accC[2], 0.f) + fmaxf(accP[2], 0.f);
    o0.w = fmaxf(accC[3], 0.f) + fmaxf(accP[3], 0.f);
    o1.x = fmaxf(accC[4], 0.f) + fmaxf(accP[4], 0.f);
    o1.y = fmaxf(accC[5], 0.f) + fmaxf(accP[5], 0.f);
    o1.z = fmaxf(accC[6], 0.f) + fmaxf(accP[6], 0.f);
    o1.w = fmaxf(accC[7], 0.f) + fmaxf(accP[7], 0.f);
    ((float4*)orow)[0] = o0;
    ((float4*)orow)[1] = o1;
  }
}

extern "C" void kernel_launch(void* const* d_in, const int* in_sizes, int n_in,
                              void* d_out, int out_size, void* d_ws, size_t ws_size,
                              hipStream_t stream)
{
  const float* x     = (const float*)d_in[0];
  const float* beta  = (const float*)d_in[1];
  const float* wq    = (const float*)d_in[2];
  const float* bq    = (const float*)d_in[3];
  const float* wk    = (const float*)d_in[4];
  const float* bk    = (const float*)d_in[5];
  const float* wv    = (const float*)d_in[6];
  const float* bv    = (const float*)d_in[7];
  const float* gamma = (const float*)d_in[8];
  const float* wch   = (const float*)d_in[9];
  const float* bch   = (const float*)d_in[10];
  const float* wpos  = (const float*)d_in[11];
  const float* bpos  = (const float*)d_in[12];
  float* out = (float*)d_out;
  float* ws  = (float*)d_ws;

  ushort* xb  = (ushort*)(ws + 0);        // 512 KB
  ushort* xtf = (ushort*)(ws + 262144);   // 512 KB
  float*  w2  = ws + 524288;              // 64 KB
  float*  b2  = ws + 540672;              // 512 B

  hipLaunchKernelGGL(k_prepalg, dim3(260), dim3(256), 0, stream,
                     x, wq, bq, wk, bk, wv, bv, gamma, wpos, bpos,
                     xb, xtf, w2, b2);
  hipLaunchKernelGGL(k_fused, dim3(64, 4), dim3(512), 0, stream,
                     xb, xtf, x, beta, wch, bch, w2, b2, out);
}

// Round 11
// 75.367 us; speedup vs baseline: 1.1539x; 1.1539x over previous
//
#include <hip/hip_runtime.h>
#include <cstddef>

// Shapes: B=4, H=W=D=16, C=32, N=4096, Dout=13; out (4,16,16,13,32) f32.

typedef float f32x4 __attribute__((ext_vector_type(4)));
typedef short s16x8 __attribute__((ext_vector_type(8)));

#define SQRT_LOG2E 1.2011224087864498f   // xb scaled so QK^T lands in exp2 domain
#define C2SHIFT    57.70780163555854f    // 40*log2(e)

// RNE f32->bf16 pack of two floats into one u32 (low = first arg). Proven R1-R10.
__device__ inline unsigned pk2(float a, float b) {
  union { float f; unsigned u; } ca, cb;
  ca.f = a; cb.f = b;
  unsigned ra = (ca.u + 0x7fffu + ((ca.u >> 16) & 1u)) >> 16;
  unsigned rb = (cb.u + 0x7fffu + ((cb.u >> 16) & 1u)) >> 16;
  return ra | (rb << 16);
}

// ---------------------------------------------------------------------------
// L1: prep only. xb = bf16(x*sqrt(log2e)) [b][n][32]; xtf = X^T A-frag tiles.
// 256 blocks x 256 thr, no LDS -> full occupancy, ~4us.
// ---------------------------------------------------------------------------
__global__ __launch_bounds__(256) void k_prep(
    const float* __restrict__ x, ushort* __restrict__ xb, ushort* __restrict__ xtf)
{
  int t = blockIdx.x * 256 + threadIdx.x;          // 0..65535
  const float4* xs = (const float4*)x;
  float4 v0 = xs[2 * t], v1 = xs[2 * t + 1];
  uint4 o;
  o.x = pk2(v0.x * SQRT_LOG2E, v0.y * SQRT_LOG2E);
  o.y = pk2(v0.z * SQRT_LOG2E, v0.w * SQRT_LOG2E);
  o.z = pk2(v1.x * SQRT_LOG2E, v1.y * SQRT_LOG2E);
  o.w = pk2(v1.z * SQRT_LOG2E, v1.w * SQRT_LOG2E);
  ((uint4*)xb)[t] = o;

  int b = t >> 14, r2 = t & 16383;
  int ktile = r2 >> 7, r3 = r2 & 127;
  int h = r3 >> 6, lane = r3 & 63;
  int g = lane >> 4, c = h * 16 + (lane & 15);
  const float* src = x + (((size_t)b * 4096 + ktile * 32 + 8 * g) * 32 + c);
  float w[8];
#pragma unroll
  for (int j = 0; j < 8; ++j) w[j] = src[(size_t)j * 32];
  uint4 u;
  u.x = pk2(w[0], w[1]); u.y = pk2(w[2], w[3]);
  u.z = pk2(w[4], w[5]); u.w = pk2(w[6], w[7]);
  ((uint4*)xtf)[(size_t)((b * 128 + ktile) * 2 + h) * 64 + lane] = u;
}

// ---------------------------------------------------------------------------
// L2: Gram (from xtf, clean b128 loads — fixes R10's 50us strided-gather tail)
// + algebra with LDS-staged weights. grid = 4 blocks (b) x 1024 thr (16 waves).
// ---------------------------------------------------------------------------
__global__ __launch_bounds__(1024) void k_alg(
    const ushort* __restrict__ xtf,
    const float* __restrict__ wq, const float* __restrict__ bq,
    const float* __restrict__ wk, const float* __restrict__ bk,
    const float* __restrict__ wv, const float* __restrict__ bv,
    const float* __restrict__ gamma,
    const float* __restrict__ wpos, const float* __restrict__ bpos,
    float* __restrict__ w2, float* __restrict__ b2)
{
  __shared__ float G[1024], s[32], t1[1024], att[1024], M[1024], mvec[32];
  __shared__ float wqS[1024], wkS[1024], wvS[1024], wpoS[4096];
  int b = blockIdx.x, tid = threadIdx.x;
  int wid = tid >> 6, lane = tid & 63, g = lane >> 4, c16 = lane & 15;
  // stage weights -> LDS (coalesced, one float4 per thread per array)
  if (tid < 256) {
    ((float4*)wqS)[tid] = ((const float4*)wq)[tid];
    ((float4*)wkS)[tid] = ((const float4*)wk)[tid];
    ((float4*)wvS)[tid] = ((const float4*)wv)[tid];
  }
  ((float4*)wpoS)[tid] = ((const float4*)wpos)[tid];
  if (tid < 1024) G[tid] = 0.f;
  if (tid < 32) s[tid] = 0.f;
  __syncthreads();

  // Stage A: Gram via MFMA on xtf fragments (A-frag(X^T) == B-frag(X))
  const ushort* xtb = xtf + (size_t)b * 131072;
  f32x4 z = {0.f, 0.f, 0.f, 0.f};
  f32x4 G00 = z, G01 = z, G10 = z, G11 = z, s0 = z, s1 = z;
  s16x8 ones;
#pragma unroll
  for (int j = 0; j < 8; ++j) ones[j] = (short)0x3F80;
  for (int t = wid * 8; t < wid * 8 + 8; ++t) {
    const ushort* xt = xtb + (size_t)t * 1024 + lane * 8;
    s16x8 a0 = *(const s16x8*)(xt);
    s16x8 a1 = *(const s16x8*)(xt + 512);
    G00 = __builtin_amdgcn_mfma_f32_16x16x32_bf16(a0, a0, G00, 0, 0, 0);
    G01 = __builtin_amdgcn_mfma_f32_16x16x32_bf16(a0, a1, G01, 0, 0, 0);
    G10 = __builtin_amdgcn_mfma_f32_16x16x32_bf16(a1, a0, G10, 0, 0, 0);
    G11 = __builtin_amdgcn_mfma_f32_16x16x32_bf16(a1, a1, G11, 0, 0, 0);
    s0  = __builtin_amdgcn_mfma_f32_16x16x32_bf16(a0, ones, s0, 0, 0, 0);
    s1  = __builtin_amdgcn_mfma_f32_16x16x32_bf16(a1, ones, s1, 0, 0, 0);
  }
#pragma unroll
  for (int hr = 0; hr < 2; ++hr)
#pragma unroll
    for (int hc = 0; hc < 2; ++hc) {
      f32x4 v = hr ? (hc ? G11 : G10) : (hc ? G01 : G00);
#pragma unroll
      for (int r = 0; r < 4; ++r)
        atomicAdd(&G[(16 * hr + 4 * g + r) * 32 + 16 * hc + c16], v[r]);
    }
  if (c16 == 0) {
#pragma unroll
    for (int hr = 0; hr < 2; ++hr) {
      f32x4 v = hr ? s1 : s0;
#pragma unroll
      for (int r = 0; r < 4; ++r) atomicAdd(&s[16 * hr + 4 * g + r], v[r]);
    }
  }
  __syncthreads();

  // Stage B (all-LDS operands), tid = (c,f)
  int c = tid >> 5, f = tid & 31;
  float t = 0.f;
#pragma unroll
  for (int j = 0; j < 32; ++j) t = fmaf(G[c * 32 + j], wkS[j * 32 + f], t);
  t1[tid] = t;
  __syncthreads();
  float swk = 0.f, swq = 0.f;
#pragma unroll
  for (int j = 0; j < 32; ++j) {
    swk = fmaf(s[j], wkS[j * 32 + f], swk);
    swq = fmaf(s[j], wqS[j * 32 + c], swq);
  }
  float e = 0.f;
#pragma unroll
  for (int i = 0; i < 32; ++i) e = fmaf(wqS[i * 32 + c], t1[i * 32 + f], e);
  e += bq[c] * (swk + 4096.f * bk[f]) + swq * bk[f];
  float m_ = e;
  for (int off = 16; off; off >>= 1) m_ = fmaxf(m_, __shfl_xor(m_, off, 32));
  float pr = __expf(e - m_);
  float sum = pr;
  for (int off = 16; off; off >>= 1) sum += __shfl_xor(sum, off, 32);
  att[tid] = pr / sum;                             // att[c][f]
  __syncthreads();
  float mm = 0.f;
#pragma unroll
  for (int j = 0; j < 32; ++j) mm = fmaf(wvS[c * 32 + j], att[f * 32 + j], mm);
  M[c * 32 + f] = mm;
  if (c == 0) {
    float mv = 0.f;
#pragma unroll
    for (int j = 0; j < 32; ++j) mv = fmaf(bv[j], att[f * 32 + j], mv);
    mvec[f] = mv;
  }
  __syncthreads();
  float gam = gamma[0];
  for (int kd = 0; kd < 4; ++kd) {
    float acc = 0.f;
#pragma unroll
    for (int j = 0; j < 32; ++j)
      acc = fmaf(M[c * 32 + j], wpoS[(kd * 32 + j) * 32 + f], acc);
    w2[((b * 4 + kd) * 32 + c) * 32 + f] = gam * acc + wpoS[(kd * 32 + c) * 32 + f];
  }
  if (c == 0) {
    float acc = 0.f;
#pragma unroll
    for (int kd = 0; kd < 4; ++kd)
#pragma unroll
      for (int j = 0; j < 32; ++j)
        acc = fmaf(mvec[j], wpoS[(kd * 32 + j) * 32 + tid], acc);
    b2[b * 32 + tid] = gam * acc + bpos[tid];
  }
}

// ---------------------------------------------------------------------------
// L3: fused flash + conv. 1024 thr (16 waves -> FORCED 4 waves/SIMD TLP).
// wid = wid2(4 row-subgroups) x kh(4 key-quarters); fixed-shift softmax =>
// partials additive; partial buffers UNION'd with conv-weight LDS (phases
// disjoint) to stay ~40KB. grid (64 rowgroups, 4 b).
// ---------------------------------------------------------------------------
union FusedSh {
  struct { f32x4 pO0[3][4][64]; f32x4 pO1[3][4][64]; float pL[3][4][64]; } ph1;
  struct { float4 wc[1024]; float4 wp[1024]; } ph2;
};

__global__ __launch_bounds__(1024) void k_fused(
    const ushort* __restrict__ xb, const ushort* __restrict__ xtf,
    const float* __restrict__ x, const float* __restrict__ beta,
    const float* __restrict__ wch, const float* __restrict__ bch,
    const float* __restrict__ w2, const float* __restrict__ b2,
    float* __restrict__ out)
{
  __shared__ FusedSh u;
  __shared__ float sS[64][32];                     // beta * attnout / L
  __shared__ float bcS[32], bpS[32];
  int rg = blockIdx.x, b = blockIdx.y, tid = threadIdx.x;
  if (tid < 32) { bcS[tid] = bch[tid]; bpS[tid] = b2[b * 32 + tid]; }

  int wid = tid >> 6, lane = tid & 63, g = lane >> 4, c16 = lane & 15;
  int wid2 = wid & 3, kh = wid >> 2;               // row-subgroup, key-quarter
  int qw = rg * 64 + wid2 * 16;
  const ushort* xbb = xb + ((size_t)b << 17);
  const ushort* xtb = xtf + (size_t)b * 131072;

  s16x8 qA = *(const s16x8*)(xbb + (qw + c16) * 32 + 8 * g);
  f32x4 z = {0.f, 0.f, 0.f, 0.f};
  f32x4 minit = {-C2SHIFT, -C2SHIFT, -C2SHIFT, -C2SHIFT};
  f32x4 oA0 = z, oA1 = z, lac = z;
  s16x8 ones;
#pragma unroll
  for (int j = 0; j < 8; ++j) ones[j] = (short)0x3F80;
  int kap = ((c16 >> 2) << 3) + (c16 & 3);         // kappa(c16)
  int k0 = kh * 1024;

  for (int kt = k0; kt < k0 + 1024; kt += 64) {
    const ushort* kra = xbb + (size_t)kt * 32;
    const ushort* krb = xbb + (size_t)(kt + 32) * 32;
    s16x8 kf0a = *(const s16x8*)(kra + (size_t)kap * 32 + 8 * g);
    s16x8 kf1a = *(const s16x8*)(kra + (size_t)(kap + 4) * 32 + 8 * g);
    s16x8 kf0b = *(const s16x8*)(krb + (size_t)kap * 32 + 8 * g);
    s16x8 kf1b = *(const s16x8*)(krb + (size_t)(kap + 4) * 32 + 8 * g);
    const ushort* xt = xtb + (size_t)(kt >> 5) * 1024 + lane * 8;
    s16x8 a0a = *(const s16x8*)(xt);
    s16x8 a1a = *(const s16x8*)(xt + 512);
    s16x8 a0b = *(const s16x8*)(xt + 1024);
    s16x8 a1b = *(const s16x8*)(xt + 1536);

    f32x4 e0 = __builtin_amdgcn_mfma_f32_16x16x32_bf16(kf0a, qA, minit, 0, 0, 0);
    f32x4 e1 = __builtin_amdgcn_mfma_f32_16x16x32_bf16(kf1a, qA, minit, 0, 0, 0);
    f32x4 e2 = __builtin_amdgcn_mfma_f32_16x16x32_bf16(kf0b, qA, minit, 0, 0, 0);
    f32x4 e3 = __builtin_amdgcn_mfma_f32_16x16x32_bf16(kf1b, qA, minit, 0, 0, 0);
    f32x4 p0, p1, p2, p3;
#pragma unroll
    for (int r = 0; r < 4; ++r) {
      p0[r] = __builtin_amdgcn_exp2f(e0[r]);
      p1[r] = __builtin_amdgcn_exp2f(e1[r]);
      p2[r] = __builtin_amdgcn_exp2f(e2[r]);
      p3[r] = __builtin_amdgcn_exp2f(e3[r]);
    }
    uint4 uA = make_uint4(pk2(p0[0], p0[1]), pk2(p0[2], p0[3]),
                          pk2(p1[0], p1[1]), pk2(p1[2], p1[3]));
    uint4 uB = make_uint4(pk2(p2[0], p2[1]), pk2(p2[2], p2[3]),
                          pk2(p3[0], p3[1]), pk2(p3[2], p3[3]));
    s16x8 fpa = __builtin_bit_cast(s16x8, uA);
    s16x8 fpb = __builtin_bit_cast(s16x8, uB);

    oA0 = __builtin_amdgcn_mfma_f32_16x16x32_bf16(a0a, fpa, oA0, 0, 0, 0);
    oA1 = __builtin_amdgcn_mfma_f32_16x16x32_bf16(a1a, fpa, oA1, 0, 0, 0);
    lac = __builtin_amdgcn_mfma_f32_16x16x32_bf16(ones, fpa, lac, 0, 0, 0);
    oA0 = __builtin_amdgcn_mfma_f32_16x16x32_bf16(a0b, fpb, oA0, 0, 0, 0);
    oA1 = __builtin_amdgcn_mfma_f32_16x16x32_bf16(a1b, fpb, oA1, 0, 0, 0);
    lac = __builtin_amdgcn_mfma_f32_16x16x32_bf16(ones, fpb, lac, 0, 0, 0);
  }

  // combine 4 key-quarters (additive: fixed softmax shift)
  if (kh != 0) {
    u.ph1.pO0[kh - 1][wid2][lane] = oA0;
    u.ph1.pO1[kh - 1][wid2][lane] = oA1;
    u.ph1.pL[kh - 1][wid2][lane] = lac[0];
  }
  __syncthreads();
  if (kh == 0) {
    float L = lac[0];
    f32x4 t0 = oA0, t1 = oA1;
#pragma unroll
    for (int q = 0; q < 3; ++q) {
      f32x4 q0 = u.ph1.pO0[q][wid2][lane], q1 = u.ph1.pO1[q][wid2][lane];
      L += u.ph1.pL[q][wid2][lane];
#pragma unroll
      for (int r = 0; r < 4; ++r) { t0[r] += q0[r]; t1[r] += q1[r]; }
    }
    float sc = beta[0] / L;
    int rloc = wid2 * 16 + c16;
    f32x4 v0, v1;
#pragma unroll
    for (int r = 0; r < 4; ++r) { v0[r] = t0[r] * sc; v1[r] = t1[r] * sc; }
    *(f32x4*)&sS[rloc][4 * g] = v0;
    *(f32x4*)&sS[rloc][16 + 4 * g] = v1;
  }
  __syncthreads();
  // stage conv weights into the union (partials dead now)
  u.ph2.wc[tid] = ((const float4*)wch)[tid];
  u.ph2.wp[tid] = ((const float4*)(w2 + (size_t)b * 4096))[tid];
  __syncthreads();

  // conv3d(1,1,4) + relu both branches; 416 active threads (52 rows x 8 fq).
  if (tid < 416) {
    int row2 = tid >> 3, fq = tid & 7;
    int hw_l = row2 / 13, dout = row2 % 13;
    int rbase = hw_l * 16 + dout;
    size_t xrow = ((size_t)b * 4096 + (size_t)(rg * 4 + hw_l) * 16 + dout) * 32;
    float accC[4], accP[4];
#pragma unroll
    for (int j = 0; j < 4; ++j) { accC[j] = bcS[fq * 4 + j]; accP[j] = bpS[fq * 4 + j]; }
    for (int kd = 0; kd < 4; ++kd) {
      const float4* xr4 = (const float4*)(x + xrow + (size_t)kd * 32);
      const float* srow = sS[rbase + kd];
#pragma unroll
      for (int c4 = 0; c4 < 8; ++c4) {
        float4 xv = xr4[c4];
#pragma unroll
        for (int e = 0; e < 4; ++e) {
          float xve = (e == 0 ? xv.x : e == 1 ? xv.y : e == 2 ? xv.z : xv.w);
          float cve = srow[4 * c4 + e] + xve;      // ca = beta*o/L + x
          int wbase = (kd * 32 + 4 * c4 + e) * 8 + fq;
          float4 w1 = u.ph2.wc[wbase];
          accC[0] = fmaf(cve, w1.x, accC[0]);
          accC[1] = fmaf(cve, w1.y, accC[1]);
          accC[2] = fmaf(cve, w1.z, accC[2]);
          accC[3] = fmaf(cve, w1.w, accC[3]);
          float4 w2v = u.ph2.wp[wbase];
          accP[0] = fmaf(xve, w2v.x, accP[0]);
          accP[1] = fmaf(xve, w2v.y, accP[1]);
          accP[2] = fmaf(xve, w2v.z, accP[2]);
          accP[3] = fmaf(xve, w2v.w, accP[3]);
        }
      }
    }
    int gid = b * 3328 + (rg * 4 + hw_l) * 13 + dout;
    float* orow = out + (size_t)gid * 32 + fq * 4;
    float4 o;
    o.x = fmaxf(accC[0], 0.f) + fmaxf(accP[0], 0.f);
    o.y = fmaxf(accC[1], 0.f) + fmaxf(accP[1], 0.f);
    o.z = fmaxf(accC[2], 0.f) + fmaxf(accP[2], 0.f);
    o.w = fmaxf(accC[3], 0.f) + fmaxf(accP[3], 0.f);
    *(float4*)orow = o;
  }
}

extern "C" void kernel_launch(void* const* d_in, const int* in_sizes, int n_in,
                              void* d_out, int out_size, void* d_ws, size_t ws_size,
                              hipStream_t stream)
{
  const float* x     = (const float*)d_in[0];
  const float* beta  = (const float*)d_in[1];
  const float* wq    = (const float*)d_in[2];
  const float* bq    = (const float*)d_in[3];
  const float* wk    = (const float*)d_in[4];
  const float* bk    = (const float*)d_in[5];
  const float* wv    = (const float*)d_in[6];
  const float* bv    = (const float*)d_in[7];
  const float* gamma = (const float*)d_in[8];
  const float* wch   = (const float*)d_in[9];
  const float* bch   = (const float*)d_in[10];
  const float* wpos  = (const float*)d_in[11];
  const float* bpos  = (const float*)d_in[12];
  float* out = (float*)d_out;
  float* ws  = (float*)d_ws;

  ushort* xb  = (ushort*)(ws + 0);        // 512 KB
  ushort* xtf = (ushort*)(ws + 262144);   // 512 KB
  float*  w2  = ws + 524288;              // 64 KB
  float*  b2  = ws + 540672;              // 512 B

  hipLaunchKernelGGL(k_prep,  dim3(256),    dim3(256),  0, stream, x, xb, xtf);
  hipLaunchKernelGGL(k_alg,   dim3(4),      dim3(1024), 0, stream,
                     xtf, wq, bq, wk, bk, wv, bv, gamma, wpos, bpos, w2, b2);
  hipLaunchKernelGGL(k_fused, dim3(64, 4),  dim3(1024), 0, stream,
                     xb, xtf, x, beta, wch, bch, w2, b2, out);
}